// Round 19
// baseline (51.846 us; speedup 1.0000x reference)
//
#include <hip/hip_runtime.h>
#include <math.h>

#define Bz 8
#define Tz 2048
#define Cz 1024
#define Hz 64
#define BT (Bz*Tz)      // 16384 rows

typedef __attribute__((ext_vector_type(8))) short bf16x8;
typedef __attribute__((ext_vector_type(4))) float f32x4;
typedef __attribute__((ext_vector_type(4))) unsigned short us4;

#define PBYTES 16896    // per-partial bytes: 128*64 bf16 O (16384) + 128 f32 l (512)

__device__ __forceinline__ unsigned short f2bf(float f) {
    union { float f; unsigned u; } v; v.f = f;
    unsigned r = v.u + 0x7fffu + ((v.u >> 16) & 1u);   // RNE
    return (unsigned short)(r >> 16);
}

__device__ __forceinline__ bf16x8 pack8(const float* s) {
    bf16x8 r;
#pragma unroll
    for (int j = 0; j < 8; j++) r[j] = (short)f2bf(s[j]);
    return r;
}

// HW packed f32->bf16 (RNE): D[15:0]=bf16(lo), D[31:16]=bf16(hi)
__device__ __forceinline__ unsigned cvt_pk_bf16(float lo, float hi) {
    unsigned r;
    asm volatile("v_cvt_pk_bf16_f32 %0, %1, %2" : "=v"(r) : "v"(lo), "v"(hi));
    return r;
}

__device__ __forceinline__ bf16x8 cvt8(float4 a, float4 b) {
    union { unsigned u[4]; bf16x8 v; } r;
    r.u[0] = cvt_pk_bf16(a.x, a.y);
    r.u[1] = cvt_pk_bf16(a.z, a.w);
    r.u[2] = cvt_pk_bf16(b.x, b.y);
    r.u[3] = cvt_pk_bf16(b.z, b.w);
    return r.v;
}

// async global->LDS, 16B/lane: lane i -> ldsbase + i*16 (wave-uniform base)
__device__ __forceinline__ void gload16(const void* g, void* l) {
    __builtin_amdgcn_global_load_lds(
        (const __attribute__((address_space(1))) void*)g,
        (__attribute__((address_space(3))) void*)l, 16, 0, 0);
}

// ---------------------------------------------------------------------------
// W prep -> per-chunk swizzled LDS image (identity-DMA format).
// img[kt*12288 + n*64 + phys*8 + e] = W[k0 + logical*8 + e][n], phys = logical^(n&7)
// ---------------------------------------------------------------------------
__global__ __launch_bounds__(256)
void wprep_kernel(const float* __restrict__ Wq, const float* __restrict__ Wk,
                  const float* __restrict__ Wv, unsigned short* __restrict__ Wti)
{
    __shared__ float T[64][65];
    const int mat = blockIdx.x >> 4;
    const int kt  = blockIdx.x & 15;
    const int k0  = kt * 64;
    const float* W = (mat == 0) ? Wq : (mat == 1) ? Wk : Wv;
    const int t  = threadIdx.x;
    const int rr = t >> 2;
    const int c4 = (t & 3) * 16;
#pragma unroll
    for (int j = 0; j < 4; j++) {
        float4 w4 = *(const float4*)&W[(size_t)(k0 + rr) * Hz + c4 + j * 4];
        T[c4 + j*4 + 0][rr] = w4.x;
        T[c4 + j*4 + 1][rr] = w4.y;
        T[c4 + j*4 + 2][rr] = w4.z;
        T[c4 + j*4 + 3][rr] = w4.w;
    }
    __syncthreads();
    const int nn  = t >> 2;
    const int sl0 = (t & 3) * 2;
    const int n   = mat * 64 + nn;
    float tmp[16];
#pragma unroll
    for (int j = 0; j < 16; j++) tmp[j] = T[nn][sl0 * 8 + j];
    unsigned short* base = &Wti[(size_t)kt * 12288 + n * 64];
    *(bf16x8*)&base[((sl0    ) ^ (n & 7)) * 8] = pack8(tmp);
    *(bf16x8*)&base[((sl0 + 1) ^ (n & 7)) * 8] = pack8(tmp + 8);
}

// ---------------------------------------------------------------------------
// QKV projection v9 (r18, best): 64 rows x 96 cols per block, grid 512
// (2 blocks/CU), counted-vmcnt distance-1, LDS 56 KB.
// q output pre-scaled by log2(e)/8.
// ---------------------------------------------------------------------------
__global__ __launch_bounds__(256, 4)
void qkv_mfma_kernel(const float* __restrict__ x, const unsigned short* __restrict__ Wti,
                     unsigned short* __restrict__ qg, unsigned short* __restrict__ kg,
                     unsigned short* __restrict__ vT)
{
    __shared__ __align__(16) float          xsF[2][64 * 64];
    __shared__ __align__(16) unsigned short ws [2][96 * 64];

    const int t    = threadIdx.x;
    const int bid  = blockIdx.x;
    const int u    = bid >> 3;
    const int cb   = u & 1;
    const int M0   = (((u >> 1) * 8) + (bid & 7)) * 64;
    const int ln   = t & 15;
    const int g    = (t & 63) >> 4;
    const int g4   = g * 4;
    const int w    = t >> 6;
    const int lane = t & 63;
    const float SCq = 0.18033688011112042f;   // log2(e)/8

    f32x4 acc[6];
#pragma unroll
    for (int i = 0; i < 6; i++) acc[i] = (f32x4){0.f, 0.f, 0.f, 0.f};

    auto issue = [&](int buf, int kt) {
        const int k0 = kt * 64;
#pragma unroll
        for (int j = 0; j < 4; j++) {
            const int r  = w * 16 + j * 4 + (lane >> 4);
            const int sl = (lane & 15) ^ (r & 7);
            gload16(&x[(size_t)(M0 + r) * Cz + k0 + sl * 4],
                    &xsF[buf][(w * 16 + j * 4) * 64]);
        }
#pragma unroll
        for (int j = 0; j < 3; j++) {
            const int jj = w * 3 + j;
            gload16(&Wti[(size_t)kt * 12288 + (size_t)(cb * 96 + jj * 8) * 64 + lane * 8],
                    &ws[buf][jj * 512]);
        }
    };

    issue(0, 0); issue(1, 1);
    asm volatile("s_waitcnt vmcnt(7)" ::: "memory");
    __builtin_amdgcn_sched_barrier(0);
    __builtin_amdgcn_s_barrier();

    for (int kt = 0; kt < 16; ++kt) {
        const int bufR = kt & 1;
        bf16x8 af[2];
        const int row = w * 16 + ln;
#pragma unroll
        for (int kc = 0; kc < 2; kc++) {
            const int s0 = kc * 8 + g * 2;
            float4 fa = *(const float4*)&xsF[bufR][row * 64 + ((s0    ) ^ (row & 7)) * 4];
            float4 fb = *(const float4*)&xsF[bufR][row * 64 + ((s0 + 1) ^ (row & 7)) * 4];
            af[kc] = cvt8(fa, fb);
        }
        __builtin_amdgcn_s_setprio(1);
#pragma unroll
        for (int ct = 0; ct < 6; ct++) {
            const int nn = ct * 16 + ln;
#pragma unroll
            for (int kc = 0; kc < 2; kc++) {
                bf16x8 bf = *(const bf16x8*)&ws[bufR][nn * 64 + ((kc*4 + g) ^ (nn & 7)) * 8];
                acc[ct] = __builtin_amdgcn_mfma_f32_16x16x32_bf16(af[kc], bf, acc[ct], 0, 0, 0);
            }
        }
        __builtin_amdgcn_s_setprio(0);

        if (kt == 15) break;

        __builtin_amdgcn_sched_barrier(0);
        __builtin_amdgcn_s_barrier();
        if (kt + 2 < 16) {
            issue(bufR, kt + 2);
            asm volatile("s_waitcnt vmcnt(7)" ::: "memory");
        } else {
            asm volatile("s_waitcnt vmcnt(0)" ::: "memory");
        }
        __builtin_amdgcn_sched_barrier(0);
        __builtin_amdgcn_s_barrier();
    }

#pragma unroll
    for (int ct = 0; ct < 6; ct++) {
        const int col0 = cb * 96 + ct * 16;
        const int mat  = col0 >> 6;
        const int cl   = (col0 & 63) + ln;
        const int m0   = M0 + w * 16 + g4;
        if (mat == 0) {
#pragma unroll
            for (int i = 0; i < 4; i++)
                qg[(size_t)(m0 + i) * Hz + cl] = f2bf(acc[ct][i] * SCq);
        } else if (mat == 1) {
#pragma unroll
            for (int i = 0; i < 4; i++)
                kg[(size_t)(m0 + i) * Hz + cl] = f2bf(acc[ct][i]);
        } else {
            const int b = m0 >> 11, tt = m0 & 2047;
            us4 pk;
#pragma unroll
            for (int i = 0; i < 4; i++) pk[i] = f2bf(acc[ct][i]);
            *(us4*)&vT[((size_t)b * Hz + cl) * Tz + tt] = pk;
        }
    }
}

// ---------------------------------------------------------------------------
// Flash attention v2: QT=128 (2 x 64-row halves per block -> 2x KV reuse),
// S-way strided KV-split, batch->XCD affinity (bid%8 = b). SWAPPED QK^T.
// Partials: O in bf16 + l in f32 (halved combine traffic).
// qt2 in 0..15; tiles s <= 2*qt2+1; qh=0 skips s=2qt2+1 (fully masked).
// ---------------------------------------------------------------------------
template<int S>
__global__ __launch_bounds__(256, 4)
void attn_mfma_kernel(const unsigned short* __restrict__ qg,
                      const unsigned short* __restrict__ kg,
                      const unsigned short* __restrict__ vT,
                      char* __restrict__ pbase)
{
    __shared__ __align__(16) unsigned short Ks [2][64 * 64];
    __shared__ __align__(16) unsigned short Vts[2][64 * 64];
    __shared__ __align__(16) unsigned short Ps [4 * 16 * 64];

    const int bid = blockIdx.x;
    const int b   = bid & 7;                   // XCD affinity
    const int idx = bid >> 3;
    const int c   = idx % S;
    const int qt2 = 15 - (idx / S);            // heavy-first
    const int smax = 2 * qt2 + 1;
    if (c > smax) return;
    const int q0  = qt2 * 128;

    const int t  = threadIdx.x;
    const int ln = t & 15;
    const int g  = (t & 63) >> 4;
    const int g4 = g * 4;
    const int w  = t >> 6;
    const int l6 = t & 63;

    const unsigned short* qb = qg + (size_t)b * Tz * Hz;
    const unsigned short* kb = kg + (size_t)b * Tz * Hz;
    const unsigned short* vb = vT + (size_t)b * Hz * Tz;

    const int rl  = l6 >> 3;
    const int swz = ((l6 & 7) ^ rl) * 8;
    auto issue_tile = [&](int buf, int s0) {
#pragma unroll
        for (int qq = 0; qq < 2; qq++) {
            const int row = w*16 + qq*8 + rl;
            gload16(&kb[(size_t)(s0 + row) * Hz + swz],
                    &Ks[buf][(w*16 + qq*8) * 64]);
            gload16(&vb[(size_t)row * Tz + s0 + swz],
                    &Vts[buf][(w*16 + qq*8) * 64]);
        }
    };

    issue_tile(0, c * 64);

    bf16x8 qf0[2], qf1[2];
    {
        const int qr0 = q0 + w*16 + ln;
        qf0[0] = *(const bf16x8*)&qb[(size_t)qr0 * Hz + g*8];
        qf0[1] = *(const bf16x8*)&qb[(size_t)qr0 * Hz + 32 + g*8];
        const int qr1 = q0 + 64 + w*16 + ln;
        qf1[0] = *(const bf16x8*)&qb[(size_t)qr1 * Hz + g*8];
        qf1[1] = *(const bf16x8*)&qb[(size_t)qr1 * Hz + 32 + g*8];
    }

    f32x4 accO0[4], accO1[4];
#pragma unroll
    for (int i = 0; i < 4; i++) {
        accO0[i] = (f32x4){0.f, 0.f, 0.f, 0.f};
        accO1[i] = (f32x4){0.f, 0.f, 0.f, 0.f};
    }
    float lrow0 = 0.f, lrow1 = 0.f;
    unsigned short* Pw = &Ps[w * 1024];
    const int pwbase = ln*64 + (g & 1) * 4;
    const int pslotx = (g >> 1);

    __syncthreads();
    int cur = 0;

// one 64-row half: QK^T (swapped) -> mask/exp2 -> P -> PV
#define DO_HALF(QF, ACCO, LROW, DIAG)                                          \
    {                                                                          \
        f32x4 accS[4];                                                         \
        __builtin_amdgcn_s_setprio(1);                                         \
        _Pragma("unroll")                                                      \
        for (int t4 = 0; t4 < 4; t4++) {                                       \
            accS[t4] = (f32x4){0.f, 0.f, 0.f, 0.f};                            \
            _Pragma("unroll")                                                  \
            for (int kc = 0; kc < 2; kc++) {                                   \
                const int n = t4*16 + ln;                                      \
                bf16x8 kf = *(const bf16x8*)&Kc[n*64 + ((kc*4 + g) ^ (n & 7)) * 8]; \
                accS[t4] = __builtin_amdgcn_mfma_f32_16x16x32_bf16(kf, QF[kc], accS[t4], 0, 0, 0); \
            }                                                                  \
        }                                                                      \
        __builtin_amdgcn_s_setprio(0);                                         \
        _Pragma("unroll")                                                      \
        for (int t4 = 0; t4 < 4; t4++) {                                       \
            float pv[4];                                                       \
            _Pragma("unroll")                                                  \
            for (int i = 0; i < 4; i++) {                                      \
                float sv = accS[t4][i];                                        \
                if ((DIAG) && (t4*16 + g4 + i > w*16 + ln)) sv = -1e30f;       \
                const float p = exp2f(sv);                                     \
                LROW += p;                                                     \
                pv[i] = p;                                                     \
            }                                                                  \
            uint2 pk2;                                                         \
            pk2.x = cvt_pk_bf16(pv[0], pv[1]);                                 \
            pk2.y = cvt_pk_bf16(pv[2], pv[3]);                                 \
            *(uint2*)&Pw[pwbase + ((t4*2 + pslotx) ^ (ln & 7)) * 8] = pk2;     \
        }                                                                      \
        __builtin_amdgcn_s_setprio(1);                                         \
        _Pragma("unroll")                                                      \
        for (int kc = 0; kc < 2; kc++) {                                       \
            bf16x8 pa = *(const bf16x8*)&Pw[ln*64 + ((kc*4 + g) ^ (ln & 7)) * 8]; \
            _Pragma("unroll")                                                  \
            for (int ht = 0; ht < 4; ht++) {                                   \
                const int vr2 = ht*16 + ln;                                    \
                bf16x8 vf = *(const bf16x8*)&Vc[vr2*64 + ((kc*4 + g) ^ (vr2 & 7)) * 8]; \
                ACCO[ht] = __builtin_amdgcn_mfma_f32_16x16x32_bf16(pa, vf, ACCO[ht], 0, 0, 0); \
            }                                                                  \
        }                                                                      \
        __builtin_amdgcn_s_setprio(0);                                         \
    }

    for (int s = c; s <= smax; s += S) {
        if (s + S <= smax) issue_tile(cur ^ 1, (s + S) * 64);

        const unsigned short* Kc = &Ks[cur][0];
        const unsigned short* Vc = &Vts[cur][0];

        if (s != smax) DO_HALF(qf0, accO0, lrow0, (s == smax - 1));
        DO_HALF(qf1, accO1, lrow1, (s == smax));

        __syncthreads();
        cur ^= 1;
    }
#undef DO_HALF

    lrow0 += __shfl_xor(lrow0, 16); lrow0 += __shfl_xor(lrow0, 32);
    lrow1 += __shfl_xor(lrow1, 16); lrow1 += __shfl_xor(lrow1, 32);

    char* Op = pbase + (size_t)((b * 16 + qt2) * S + c) * PBYTES;
    unsigned short* Ob = (unsigned short*)Op;
    float* Lp = (float*)(Op + 16384);
#pragma unroll
    for (int ht = 0; ht < 4; ht++)
#pragma unroll
        for (int i = 0; i < 4; i++) {
            Ob[(size_t)(w*16 + g4 + i) * 64 + ht*16 + ln]        = f2bf(accO0[ht][i]);
            Ob[(size_t)(64 + w*16 + g4 + i) * 64 + ht*16 + ln]   = f2bf(accO1[ht][i]);
        }
    if (g == 0) {
        Lp[w*16 + ln]      = lrow0;
        Lp[64 + w*16 + ln] = lrow1;
    }
}

// ---------------------------------------------------------------------------
// Combine: out = sum_c O_c / sum_c l_c (O bf16, l f32). 128 blocks (b,qt2),
// 256 thr: row = t>>1 (0..127), half-row cols = (t&1)*32.
// ---------------------------------------------------------------------------
template<int S>
__global__ __launch_bounds__(256)
void combine_kernel(const char* __restrict__ pbase, float* __restrict__ out)
{
    const int bid = blockIdx.x;
    const int b   = bid & 7;
    const int qt2 = bid >> 3;
    const int t   = threadIdx.x;
    const int r   = t >> 1;
    const int cg  = (t & 1) * 32;

    const int nch = (2*qt2 + 2 < S) ? (2*qt2 + 2) : S;
    const char* P0 = pbase + (size_t)((b * 16 + qt2) * S) * PBYTES;

    float denom = 0.f;
    float o[32];
#pragma unroll
    for (int j = 0; j < 32; j++) o[j] = 0.f;
    for (int cc = 0; cc < nch; cc++) {
        const char* Pc = P0 + (size_t)cc * PBYTES;
        const unsigned short* Ob = (const unsigned short*)Pc;
        denom += ((const float*)(Pc + 16384))[r];
#pragma unroll
        for (int j = 0; j < 8; j++) {
            us4 v = *(const us4*)&Ob[(size_t)r * 64 + cg + j * 4];
#pragma unroll
            for (int e = 0; e < 4; e++) {
                union { unsigned u; float f; } cv;
                cv.u = ((unsigned)v[e]) << 16;
                o[j*4 + e] += cv.f;
            }
        }
    }
    const float inv = 1.f / denom;
    float* ob = out + ((size_t)b * Tz + qt2 * 128 + r) * Hz + cg;
#pragma unroll
    for (int j = 0; j < 8; j++)
        *(float4*)&ob[j * 4] = make_float4(o[j*4] * inv, o[j*4+1] * inv,
                                           o[j*4+2] * inv, o[j*4+3] * inv);
}

extern "C" void kernel_launch(void* const* d_in, const int* in_sizes, int n_in,
                              void* d_out, int out_size, void* d_ws, size_t ws_size,
                              hipStream_t stream) {
    const float* x  = (const float*)d_in[0];
    const float* Wq = (const float*)d_in[1];
    const float* Wk = (const float*)d_in[2];
    const float* Wv = (const float*)d_in[3];

    unsigned short* Wti = (unsigned short*)d_ws;           // 16*12288 = 196608
    unsigned short* qg  = Wti + 196608;
    unsigned short* kg  = qg + (size_t)BT * Hz;
    unsigned short* vT  = kg + (size_t)BT * Hz;            // [b][h][t]
    const size_t baseShorts = 196608 + 3 * (size_t)BT * Hz;
    char* pbase = (char*)d_ws + baseShorts * 2;
    float* out = (float*)d_out;

    wprep_kernel<<<48, 256, 0, stream>>>(Wq, Wk, Wv, Wti);
    qkv_mfma_kernel<<<512, 256, 0, stream>>>(x, Wti, qg, kg, vT);

    const size_t base = baseShorts * 2;
    const size_t per  = (size_t)8 * 16 * PBYTES;           // bytes per split-way
    if (ws_size >= base + 4 * per) {
        attn_mfma_kernel<4><<<16 * 4 * 8, 256, 0, stream>>>(qg, kg, vT, pbase);
        combine_kernel<4><<<128, 256, 0, stream>>>(pbase, out);
    } else {
        attn_mfma_kernel<1><<<16 * 1 * 8, 256, 0, stream>>>(qg, kg, vT, pbase);
        combine_kernel<1><<<128, 256, 0, stream>>>(pbase, out);
    }
}

// Round 20
// 46.047 us; speedup vs baseline: 1.1259x; 1.1259x over previous
//
#include <hip/hip_runtime.h>
#include <math.h>

#define Bz 8
#define Tz 2048
#define Cz 1024
#define Hz 64
#define BT (Bz*Tz)      // 16384 rows

typedef __attribute__((ext_vector_type(8))) short bf16x8;
typedef __attribute__((ext_vector_type(4))) float f32x4;
typedef __attribute__((ext_vector_type(4))) unsigned short us4;

#define PBYTES 8448     // per-partial bytes: 64*64 bf16 O (8192) + 64 f32 l (256)

__device__ __forceinline__ unsigned short f2bf(float f) {
    union { float f; unsigned u; } v; v.f = f;
    unsigned r = v.u + 0x7fffu + ((v.u >> 16) & 1u);   // RNE
    return (unsigned short)(r >> 16);
}

__device__ __forceinline__ bf16x8 pack8(const float* s) {
    bf16x8 r;
#pragma unroll
    for (int j = 0; j < 8; j++) r[j] = (short)f2bf(s[j]);
    return r;
}

// HW packed f32->bf16 (RNE): D[15:0]=bf16(lo), D[31:16]=bf16(hi)
__device__ __forceinline__ unsigned cvt_pk_bf16(float lo, float hi) {
    unsigned r;
    asm volatile("v_cvt_pk_bf16_f32 %0, %1, %2" : "=v"(r) : "v"(lo), "v"(hi));
    return r;
}

__device__ __forceinline__ bf16x8 cvt8(float4 a, float4 b) {
    union { unsigned u[4]; bf16x8 v; } r;
    r.u[0] = cvt_pk_bf16(a.x, a.y);
    r.u[1] = cvt_pk_bf16(a.z, a.w);
    r.u[2] = cvt_pk_bf16(b.x, b.y);
    r.u[3] = cvt_pk_bf16(b.z, b.w);
    return r.v;
}

// async global->LDS, 16B/lane: lane i -> ldsbase + i*16 (wave-uniform base)
__device__ __forceinline__ void gload16(const void* g, void* l) {
    __builtin_amdgcn_global_load_lds(
        (const __attribute__((address_space(1))) void*)g,
        (__attribute__((address_space(3))) void*)l, 16, 0, 0);
}

// ---------------------------------------------------------------------------
// W prep -> per-chunk swizzled LDS image (identity-DMA format).
// img[kt*12288 + n*64 + phys*8 + e] = W[k0 + logical*8 + e][n], phys = logical^(n&7)
// ---------------------------------------------------------------------------
__global__ __launch_bounds__(256)
void wprep_kernel(const float* __restrict__ Wq, const float* __restrict__ Wk,
                  const float* __restrict__ Wv, unsigned short* __restrict__ Wti)
{
    __shared__ float T[64][65];
    const int mat = blockIdx.x >> 4;
    const int kt  = blockIdx.x & 15;
    const int k0  = kt * 64;
    const float* W = (mat == 0) ? Wq : (mat == 1) ? Wk : Wv;
    const int t  = threadIdx.x;
    const int rr = t >> 2;
    const int c4 = (t & 3) * 16;
#pragma unroll
    for (int j = 0; j < 4; j++) {
        float4 w4 = *(const float4*)&W[(size_t)(k0 + rr) * Hz + c4 + j * 4];
        T[c4 + j*4 + 0][rr] = w4.x;
        T[c4 + j*4 + 1][rr] = w4.y;
        T[c4 + j*4 + 2][rr] = w4.z;
        T[c4 + j*4 + 3][rr] = w4.w;
    }
    __syncthreads();
    const int nn  = t >> 2;
    const int sl0 = (t & 3) * 2;
    const int n   = mat * 64 + nn;
    float tmp[16];
#pragma unroll
    for (int j = 0; j < 16; j++) tmp[j] = T[nn][sl0 * 8 + j];
    unsigned short* base = &Wti[(size_t)kt * 12288 + n * 64];
    *(bf16x8*)&base[((sl0    ) ^ (n & 7)) * 8] = pack8(tmp);
    *(bf16x8*)&base[((sl0 + 1) ^ (n & 7)) * 8] = pack8(tmp + 8);
}

// ---------------------------------------------------------------------------
// QKV projection v9 (r18, best): 64 rows x 96 cols per block, grid 512
// (2 blocks/CU), counted-vmcnt distance-1, LDS 56 KB.
// q output pre-scaled by log2(e)/8.
// ---------------------------------------------------------------------------
__global__ __launch_bounds__(256, 4)
void qkv_mfma_kernel(const float* __restrict__ x, const unsigned short* __restrict__ Wti,
                     unsigned short* __restrict__ qg, unsigned short* __restrict__ kg,
                     unsigned short* __restrict__ vT)
{
    __shared__ __align__(16) float          xsF[2][64 * 64];
    __shared__ __align__(16) unsigned short ws [2][96 * 64];

    const int t    = threadIdx.x;
    const int bid  = blockIdx.x;
    const int u    = bid >> 3;
    const int cb   = u & 1;
    const int M0   = (((u >> 1) * 8) + (bid & 7)) * 64;
    const int ln   = t & 15;
    const int g    = (t & 63) >> 4;
    const int g4   = g * 4;
    const int w    = t >> 6;
    const int lane = t & 63;
    const float SCq = 0.18033688011112042f;   // log2(e)/8

    f32x4 acc[6];
#pragma unroll
    for (int i = 0; i < 6; i++) acc[i] = (f32x4){0.f, 0.f, 0.f, 0.f};

    auto issue = [&](int buf, int kt) {
        const int k0 = kt * 64;
#pragma unroll
        for (int j = 0; j < 4; j++) {
            const int r  = w * 16 + j * 4 + (lane >> 4);
            const int sl = (lane & 15) ^ (r & 7);
            gload16(&x[(size_t)(M0 + r) * Cz + k0 + sl * 4],
                    &xsF[buf][(w * 16 + j * 4) * 64]);
        }
#pragma unroll
        for (int j = 0; j < 3; j++) {
            const int jj = w * 3 + j;
            gload16(&Wti[(size_t)kt * 12288 + (size_t)(cb * 96 + jj * 8) * 64 + lane * 8],
                    &ws[buf][jj * 512]);
        }
    };

    issue(0, 0); issue(1, 1);
    asm volatile("s_waitcnt vmcnt(7)" ::: "memory");
    __builtin_amdgcn_sched_barrier(0);
    __builtin_amdgcn_s_barrier();

    for (int kt = 0; kt < 16; ++kt) {
        const int bufR = kt & 1;
        bf16x8 af[2];
        const int row = w * 16 + ln;
#pragma unroll
        for (int kc = 0; kc < 2; kc++) {
            const int s0 = kc * 8 + g * 2;
            float4 fa = *(const float4*)&xsF[bufR][row * 64 + ((s0    ) ^ (row & 7)) * 4];
            float4 fb = *(const float4*)&xsF[bufR][row * 64 + ((s0 + 1) ^ (row & 7)) * 4];
            af[kc] = cvt8(fa, fb);
        }
        __builtin_amdgcn_s_setprio(1);
#pragma unroll
        for (int ct = 0; ct < 6; ct++) {
            const int nn = ct * 16 + ln;
#pragma unroll
            for (int kc = 0; kc < 2; kc++) {
                bf16x8 bf = *(const bf16x8*)&ws[bufR][nn * 64 + ((kc*4 + g) ^ (nn & 7)) * 8];
                acc[ct] = __builtin_amdgcn_mfma_f32_16x16x32_bf16(af[kc], bf, acc[ct], 0, 0, 0);
            }
        }
        __builtin_amdgcn_s_setprio(0);

        if (kt == 15) break;

        __builtin_amdgcn_sched_barrier(0);
        __builtin_amdgcn_s_barrier();
        if (kt + 2 < 16) {
            issue(bufR, kt + 2);
            asm volatile("s_waitcnt vmcnt(7)" ::: "memory");
        } else {
            asm volatile("s_waitcnt vmcnt(0)" ::: "memory");
        }
        __builtin_amdgcn_sched_barrier(0);
        __builtin_amdgcn_s_barrier();
    }

#pragma unroll
    for (int ct = 0; ct < 6; ct++) {
        const int col0 = cb * 96 + ct * 16;
        const int mat  = col0 >> 6;
        const int cl   = (col0 & 63) + ln;
        const int m0   = M0 + w * 16 + g4;
        if (mat == 0) {
#pragma unroll
            for (int i = 0; i < 4; i++)
                qg[(size_t)(m0 + i) * Hz + cl] = f2bf(acc[ct][i] * SCq);
        } else if (mat == 1) {
#pragma unroll
            for (int i = 0; i < 4; i++)
                kg[(size_t)(m0 + i) * Hz + cl] = f2bf(acc[ct][i]);
        } else {
            const int b = m0 >> 11, tt = m0 & 2047;
            us4 pk;
#pragma unroll
            for (int i = 0; i < 4; i++) pk[i] = f2bf(acc[ct][i]);
            *(us4*)&vT[((size_t)b * Hz + cl) * Tz + tt] = pk;
        }
    }
}

// ---------------------------------------------------------------------------
// Flash attention (r18 structure), S-way strided KV-split, batch->XCD
// affinity (bid%8 = b). SWAPPED QK^T -> C[kv][q], lane owns q-row ln.
// Fixed-max softmax p=exp2(s). Double-buffered gload_lds, ONE barrier/tile.
// Partials: O in bf16 + l in f32 (r19-validated, halves combine traffic).
// ---------------------------------------------------------------------------
template<int S>
__global__ __launch_bounds__(256, 4)
void attn_mfma_kernel(const unsigned short* __restrict__ qg,
                      const unsigned short* __restrict__ kg,
                      const unsigned short* __restrict__ vT,
                      char* __restrict__ pbase)
{
    __shared__ __align__(16) unsigned short Ks [2][64 * 64];
    __shared__ __align__(16) unsigned short Vts[2][64 * 64];
    __shared__ __align__(16) unsigned short Ps [4 * 16 * 64];

    const int bid = blockIdx.x;
    const int b   = bid & 7;                   // XCD affinity
    const int r0  = bid >> 3;
    const int c   = r0 % S;
    const int qt  = 31 - (r0 / S);             // heavy-first
    if (c > qt) return;
    const int q0  = qt * 64;

    const int t  = threadIdx.x;
    const int ln = t & 15;
    const int g  = (t & 63) >> 4;
    const int g4 = g * 4;
    const int w  = t >> 6;
    const int l6 = t & 63;

    const unsigned short* qb = qg + (size_t)b * Tz * Hz;
    const unsigned short* kb = kg + (size_t)b * Tz * Hz;
    const unsigned short* vb = vT + (size_t)b * Hz * Tz;

    const int rl  = l6 >> 3;
    const int swz = ((l6 & 7) ^ rl) * 8;
    auto issue_tile = [&](int buf, int s0) {
#pragma unroll
        for (int qq = 0; qq < 2; qq++) {
            const int row = w*16 + qq*8 + rl;
            gload16(&kb[(size_t)(s0 + row) * Hz + swz],
                    &Ks[buf][(w*16 + qq*8) * 64]);
            gload16(&vb[(size_t)row * Tz + s0 + swz],
                    &Vts[buf][(w*16 + qq*8) * 64]);
        }
    };

    issue_tile(0, c * 64);

    bf16x8 qf[2];
    {
        const int qrow = q0 + w*16 + ln;
        qf[0] = *(const bf16x8*)&qb[(size_t)qrow * Hz + g*8];
        qf[1] = *(const bf16x8*)&qb[(size_t)qrow * Hz + 32 + g*8];
    }

    f32x4 accO[4];
#pragma unroll
    for (int i = 0; i < 4; i++) accO[i] = (f32x4){0.f, 0.f, 0.f, 0.f};
    float lrow = 0.f;
    unsigned short* Pw = &Ps[w * 1024];
    const int pwbase = ln*64 + (g & 1) * 4;
    const int pslotx = (g >> 1);

    __syncthreads();
    int cur = 0;

    for (int s = c; s <= qt; s += S) {
        if (s + S <= qt) issue_tile(cur ^ 1, (s + S) * 64);

        const unsigned short* Kc = &Ks[cur][0];
        const unsigned short* Vc = &Vts[cur][0];

        // S^T = K Q^T : lane holds C[kv = t4*16 + g4 + i][q = ln]
        f32x4 accS[4];
        __builtin_amdgcn_s_setprio(1);
#pragma unroll
        for (int t4 = 0; t4 < 4; t4++) {
            accS[t4] = (f32x4){0.f, 0.f, 0.f, 0.f};
#pragma unroll
            for (int kc = 0; kc < 2; kc++) {
                const int n = t4*16 + ln;
                bf16x8 kf = *(const bf16x8*)&Kc[n*64 + ((kc*4 + g) ^ (n & 7)) * 8];
                accS[t4] = __builtin_amdgcn_mfma_f32_16x16x32_bf16(kf, qf[kc], accS[t4], 0, 0, 0);
            }
        }
        __builtin_amdgcn_s_setprio(0);

        const bool diag = (s == qt);
#pragma unroll
        for (int t4 = 0; t4 < 4; t4++) {
            float pv[4];
#pragma unroll
            for (int i = 0; i < 4; i++) {
                float sv = accS[t4][i];
                if (diag && (t4*16 + g4 + i > w*16 + ln)) sv = -1e30f;  // kv > q
                const float p = exp2f(sv);
                lrow += p;
                pv[i] = p;
            }
            uint2 pk2;
            pk2.x = cvt_pk_bf16(pv[0], pv[1]);
            pk2.y = cvt_pk_bf16(pv[2], pv[3]);
            *(uint2*)&Pw[pwbase + ((t4*2 + pslotx) ^ (ln & 7)) * 8] = pk2;
        }

        __builtin_amdgcn_s_setprio(1);
#pragma unroll
        for (int kc = 0; kc < 2; kc++) {
            bf16x8 pa = *(const bf16x8*)&Pw[ln*64 + ((kc*4 + g) ^ (ln & 7)) * 8];
#pragma unroll
            for (int ht = 0; ht < 4; ht++) {
                const int vr2 = ht*16 + ln;
                bf16x8 vf = *(const bf16x8*)&Vc[vr2*64 + ((kc*4 + g) ^ (vr2 & 7)) * 8];
                accO[ht] = __builtin_amdgcn_mfma_f32_16x16x32_bf16(pa, vf, accO[ht], 0, 0, 0);
            }
        }
        __builtin_amdgcn_s_setprio(0);

        __syncthreads();
        cur ^= 1;
    }

    // full row-sum for q-row ln: sum across the 4 g-lanes
    lrow += __shfl_xor(lrow, 16);
    lrow += __shfl_xor(lrow, 32);

    char* Op = pbase + (size_t)((b * 32 + qt) * S + c) * PBYTES;
    unsigned short* Ob = (unsigned short*)Op;
    float* Lp = (float*)(Op + 8192);
#pragma unroll
    for (int ht = 0; ht < 4; ht++)
#pragma unroll
        for (int i = 0; i < 4; i++)
            Ob[(size_t)(w*16 + g4 + i) * 64 + ht*16 + ln] = f2bf(accO[ht][i]);
    if (g == 0)
        Lp[w*16 + ln] = lrow;
}

// ---------------------------------------------------------------------------
// Combine: out = sum_c O_c / sum_c l_c (O bf16, l f32). 256 blocks (b,qt),
// 256 thr: row = t>>2 (0..63), colgroup = t&3 (16 cols).
// bid%8 = b -> same XCD as producers.
// ---------------------------------------------------------------------------
template<int S>
__global__ __launch_bounds__(256)
void combine_kernel(const char* __restrict__ pbase, float* __restrict__ out)
{
    const int bid = blockIdx.x;
    const int b   = bid & 7;
    const int qt  = 31 - (bid >> 3);
    const int t   = threadIdx.x;
    const int r   = t >> 2;
    const int cg  = t & 3;

    const int nch = (qt + 1 < S) ? (qt + 1) : S;
    const char* P0 = pbase + (size_t)(b * 32 + qt) * S * PBYTES;

    float denom = 0.f;
    float o[16];
#pragma unroll
    for (int j = 0; j < 16; j++) o[j] = 0.f;
    for (int cc = 0; cc < nch; cc++) {
        const char* Pc = P0 + (size_t)cc * PBYTES;
        const unsigned short* Ob = (const unsigned short*)Pc;
        denom += ((const float*)(Pc + 8192))[r];
#pragma unroll
        for (int j = 0; j < 4; j++) {
            us4 v = *(const us4*)&Ob[(size_t)r * 64 + cg * 16 + j * 4];
#pragma unroll
            for (int e = 0; e < 4; e++) {
                union { unsigned u; float f; } cv;
                cv.u = ((unsigned)v[e]) << 16;
                o[j*4 + e] += cv.f;
            }
        }
    }
    const float inv = 1.f / denom;
    float* ob = out + ((size_t)b * Tz + qt * 64 + r) * Hz + cg * 16;
#pragma unroll
    for (int j = 0; j < 4; j++)
        *(float4*)&ob[j * 4] = make_float4(o[j*4] * inv, o[j*4+1] * inv,
                                           o[j*4+2] * inv, o[j*4+3] * inv);
}

extern "C" void kernel_launch(void* const* d_in, const int* in_sizes, int n_in,
                              void* d_out, int out_size, void* d_ws, size_t ws_size,
                              hipStream_t stream) {
    const float* x  = (const float*)d_in[0];
    const float* Wq = (const float*)d_in[1];
    const float* Wk = (const float*)d_in[2];
    const float* Wv = (const float*)d_in[3];

    unsigned short* Wti = (unsigned short*)d_ws;           // 16*12288 = 196608
    unsigned short* qg  = Wti + 196608;
    unsigned short* kg  = qg + (size_t)BT * Hz;
    unsigned short* vT  = kg + (size_t)BT * Hz;            // [b][h][t]
    const size_t baseShorts = 196608 + 3 * (size_t)BT * Hz;
    char* pbase = (char*)d_ws + baseShorts * 2;
    float* out = (float*)d_out;

    wprep_kernel<<<48, 256, 0, stream>>>(Wq, Wk, Wv, Wti);
    qkv_mfma_kernel<<<512, 256, 0, stream>>>(x, Wti, qg, kg, vT);

    const size_t base = baseShorts * 2;
    const size_t per  = (size_t)8 * 32 * PBYTES;           // bytes per split-way
    if (ws_size >= base + 4 * per) {
        attn_mfma_kernel<4><<<8 * 32 * 4, 256, 0, stream>>>(qg, kg, vT, pbase);
        combine_kernel<4><<<256, 256, 0, stream>>>(pbase, out);
    } else {
        attn_mfma_kernel<1><<<8 * 32 * 1, 256, 0, stream>>>(qg, kg, vT, pbase);
        combine_kernel<1><<<256, 256, 0, stream>>>(pbase, out);
    }
}

// Round 21
// 45.944 us; speedup vs baseline: 1.1285x; 1.0022x over previous
//
#include <hip/hip_runtime.h>
#include <math.h>

#define Bz 8
#define Tz 2048
#define Cz 1024
#define Hz 64
#define BT (Bz*Tz)      // 16384 rows

typedef __attribute__((ext_vector_type(8))) short bf16x8;
typedef __attribute__((ext_vector_type(4))) float f32x4;
typedef __attribute__((ext_vector_type(4))) unsigned short us4;

#define PBYTES 8448     // per-partial bytes: 64*64 bf16 O (8192) + 64 f32 l (256)

__device__ __forceinline__ unsigned short f2bf(float f) {
    union { float f; unsigned u; } v; v.f = f;
    unsigned r = v.u + 0x7fffu + ((v.u >> 16) & 1u);   // RNE
    return (unsigned short)(r >> 16);
}

__device__ __forceinline__ bf16x8 pack8(const float* s) {
    bf16x8 r;
#pragma unroll
    for (int j = 0; j < 8; j++) r[j] = (short)f2bf(s[j]);
    return r;
}

// HW packed f32->bf16 (RNE): D[15:0]=bf16(lo), D[31:16]=bf16(hi)
__device__ __forceinline__ unsigned cvt_pk_bf16(float lo, float hi) {
    unsigned r;
    asm volatile("v_cvt_pk_bf16_f32 %0, %1, %2" : "=v"(r) : "v"(lo), "v"(hi));
    return r;
}

__device__ __forceinline__ bf16x8 cvt8(float4 a, float4 b) {
    union { unsigned u[4]; bf16x8 v; } r;
    r.u[0] = cvt_pk_bf16(a.x, a.y);
    r.u[1] = cvt_pk_bf16(a.z, a.w);
    r.u[2] = cvt_pk_bf16(b.x, b.y);
    r.u[3] = cvt_pk_bf16(b.z, b.w);
    return r.v;
}

// async global->LDS, 16B/lane: lane i -> ldsbase + i*16 (wave-uniform base)
__device__ __forceinline__ void gload16(const void* g, void* l) {
    __builtin_amdgcn_global_load_lds(
        (const __attribute__((address_space(1))) void*)g,
        (__attribute__((address_space(3))) void*)l, 16, 0, 0);
}

// ---------------------------------------------------------------------------
// W prep -> per-chunk swizzled LDS image (identity-DMA format).
// img[kt*12288 + n*64 + phys*8 + e] = W[k0 + logical*8 + e][n], phys = logical^(n&7)
// ---------------------------------------------------------------------------
__global__ __launch_bounds__(256)
void wprep_kernel(const float* __restrict__ Wq, const float* __restrict__ Wk,
                  const float* __restrict__ Wv, unsigned short* __restrict__ Wti)
{
    __shared__ float T[64][65];
    const int mat = blockIdx.x >> 4;
    const int kt  = blockIdx.x & 15;
    const int k0  = kt * 64;
    const float* W = (mat == 0) ? Wq : (mat == 1) ? Wk : Wv;
    const int t  = threadIdx.x;
    const int rr = t >> 2;
    const int c4 = (t & 3) * 16;
#pragma unroll
    for (int j = 0; j < 4; j++) {
        float4 w4 = *(const float4*)&W[(size_t)(k0 + rr) * Hz + c4 + j * 4];
        T[c4 + j*4 + 0][rr] = w4.x;
        T[c4 + j*4 + 1][rr] = w4.y;
        T[c4 + j*4 + 2][rr] = w4.z;
        T[c4 + j*4 + 3][rr] = w4.w;
    }
    __syncthreads();
    const int nn  = t >> 2;
    const int sl0 = (t & 3) * 2;
    const int n   = mat * 64 + nn;
    float tmp[16];
#pragma unroll
    for (int j = 0; j < 16; j++) tmp[j] = T[nn][sl0 * 8 + j];
    unsigned short* base = &Wti[(size_t)kt * 12288 + n * 64];
    *(bf16x8*)&base[((sl0    ) ^ (n & 7)) * 8] = pack8(tmp);
    *(bf16x8*)&base[((sl0 + 1) ^ (n & 7)) * 8] = pack8(tmp + 8);
}

// ---------------------------------------------------------------------------
// QKV projection v9 (r18/r20): 64 rows x 96 cols per block, grid 512
// (2 blocks/CU), counted-vmcnt distance-1, LDS 56 KB. x issued before W
// (HBM loads get head start). q output pre-scaled by log2(e)/8.
// ---------------------------------------------------------------------------
__global__ __launch_bounds__(256, 4)
void qkv_mfma_kernel(const float* __restrict__ x, const unsigned short* __restrict__ Wti,
                     unsigned short* __restrict__ qg, unsigned short* __restrict__ kg,
                     unsigned short* __restrict__ vT)
{
    __shared__ __align__(16) float          xsF[2][64 * 64];
    __shared__ __align__(16) unsigned short ws [2][96 * 64];

    const int t    = threadIdx.x;
    const int bid  = blockIdx.x;
    const int u    = bid >> 3;
    const int cb   = u & 1;
    const int M0   = (((u >> 1) * 8) + (bid & 7)) * 64;
    const int ln   = t & 15;
    const int g    = (t & 63) >> 4;
    const int g4   = g * 4;
    const int w    = t >> 6;
    const int lane = t & 63;
    const float SCq = 0.18033688011112042f;   // log2(e)/8

    f32x4 acc[6];
#pragma unroll
    for (int i = 0; i < 6; i++) acc[i] = (f32x4){0.f, 0.f, 0.f, 0.f};

    auto issue = [&](int buf, int kt) {
        const int k0 = kt * 64;
#pragma unroll
        for (int j = 0; j < 4; j++) {
            const int r  = w * 16 + j * 4 + (lane >> 4);
            const int sl = (lane & 15) ^ (r & 7);
            gload16(&x[(size_t)(M0 + r) * Cz + k0 + sl * 4],
                    &xsF[buf][(w * 16 + j * 4) * 64]);
        }
#pragma unroll
        for (int j = 0; j < 3; j++) {
            const int jj = w * 3 + j;
            gload16(&Wti[(size_t)kt * 12288 + (size_t)(cb * 96 + jj * 8) * 64 + lane * 8],
                    &ws[buf][jj * 512]);
        }
    };

    issue(0, 0); issue(1, 1);
    asm volatile("s_waitcnt vmcnt(7)" ::: "memory");
    __builtin_amdgcn_sched_barrier(0);
    __builtin_amdgcn_s_barrier();

    for (int kt = 0; kt < 16; ++kt) {
        const int bufR = kt & 1;
        bf16x8 af[2];
        const int row = w * 16 + ln;
#pragma unroll
        for (int kc = 0; kc < 2; kc++) {
            const int s0 = kc * 8 + g * 2;
            float4 fa = *(const float4*)&xsF[bufR][row * 64 + ((s0    ) ^ (row & 7)) * 4];
            float4 fb = *(const float4*)&xsF[bufR][row * 64 + ((s0 + 1) ^ (row & 7)) * 4];
            af[kc] = cvt8(fa, fb);
        }
        __builtin_amdgcn_s_setprio(1);
#pragma unroll
        for (int ct = 0; ct < 6; ct++) {
            const int nn = ct * 16 + ln;
#pragma unroll
            for (int kc = 0; kc < 2; kc++) {
                bf16x8 bf = *(const bf16x8*)&ws[bufR][nn * 64 + ((kc*4 + g) ^ (nn & 7)) * 8];
                acc[ct] = __builtin_amdgcn_mfma_f32_16x16x32_bf16(af[kc], bf, acc[ct], 0, 0, 0);
            }
        }
        __builtin_amdgcn_s_setprio(0);

        if (kt == 15) break;

        __builtin_amdgcn_sched_barrier(0);
        __builtin_amdgcn_s_barrier();
        if (kt + 2 < 16) {
            issue(bufR, kt + 2);
            asm volatile("s_waitcnt vmcnt(7)" ::: "memory");
        } else {
            asm volatile("s_waitcnt vmcnt(0)" ::: "memory");
        }
        __builtin_amdgcn_sched_barrier(0);
        __builtin_amdgcn_s_barrier();
    }

#pragma unroll
    for (int ct = 0; ct < 6; ct++) {
        const int col0 = cb * 96 + ct * 16;
        const int mat  = col0 >> 6;
        const int cl   = (col0 & 63) + ln;
        const int m0   = M0 + w * 16 + g4;
        if (mat == 0) {
#pragma unroll
            for (int i = 0; i < 4; i++)
                qg[(size_t)(m0 + i) * Hz + cl] = f2bf(acc[ct][i] * SCq);
        } else if (mat == 1) {
#pragma unroll
            for (int i = 0; i < 4; i++)
                kg[(size_t)(m0 + i) * Hz + cl] = f2bf(acc[ct][i]);
        } else {
            const int b = m0 >> 11, tt = m0 & 2047;
            us4 pk;
#pragma unroll
            for (int i = 0; i < 4; i++) pk[i] = f2bf(acc[ct][i]);
            *(us4*)&vT[((size_t)b * Hz + cl) * Tz + tt] = pk;
        }
    }
}

// ---------------------------------------------------------------------------
// Flash attention (r20), S-way strided KV-split, batch->XCD affinity.
// SWAPPED QK^T; fixed-max softmax; dbuf gload_lds, ONE barrier/tile
// (skipped on the final tile). Partials: O bf16 + l f32.
// ---------------------------------------------------------------------------
template<int S>
__global__ __launch_bounds__(256, 4)
void attn_mfma_kernel(const unsigned short* __restrict__ qg,
                      const unsigned short* __restrict__ kg,
                      const unsigned short* __restrict__ vT,
                      char* __restrict__ pbase)
{
    __shared__ __align__(16) unsigned short Ks [2][64 * 64];
    __shared__ __align__(16) unsigned short Vts[2][64 * 64];
    __shared__ __align__(16) unsigned short Ps [4 * 16 * 64];

    const int bid = blockIdx.x;
    const int b   = bid & 7;                   // XCD affinity
    const int r0  = bid >> 3;
    const int c   = r0 % S;
    const int qt  = 31 - (r0 / S);             // heavy-first
    if (c > qt) return;
    const int q0  = qt * 64;

    const int t  = threadIdx.x;
    const int ln = t & 15;
    const int g  = (t & 63) >> 4;
    const int g4 = g * 4;
    const int w  = t >> 6;
    const int l6 = t & 63;

    const unsigned short* qb = qg + (size_t)b * Tz * Hz;
    const unsigned short* kb = kg + (size_t)b * Tz * Hz;
    const unsigned short* vb = vT + (size_t)b * Hz * Tz;

    const int rl  = l6 >> 3;
    const int swz = ((l6 & 7) ^ rl) * 8;
    auto issue_tile = [&](int buf, int s0) {
#pragma unroll
        for (int qq = 0; qq < 2; qq++) {
            const int row = w*16 + qq*8 + rl;
            gload16(&kb[(size_t)(s0 + row) * Hz + swz],
                    &Ks[buf][(w*16 + qq*8) * 64]);
            gload16(&vb[(size_t)row * Tz + s0 + swz],
                    &Vts[buf][(w*16 + qq*8) * 64]);
        }
    };

    issue_tile(0, c * 64);

    bf16x8 qf[2];
    {
        const int qrow = q0 + w*16 + ln;
        qf[0] = *(const bf16x8*)&qb[(size_t)qrow * Hz + g*8];
        qf[1] = *(const bf16x8*)&qb[(size_t)qrow * Hz + 32 + g*8];
    }

    f32x4 accO[4];
#pragma unroll
    for (int i = 0; i < 4; i++) accO[i] = (f32x4){0.f, 0.f, 0.f, 0.f};
    float lrow = 0.f;
    unsigned short* Pw = &Ps[w * 1024];
    const int pwbase = ln*64 + (g & 1) * 4;
    const int pslotx = (g >> 1);

    __syncthreads();
    int cur = 0;

    for (int s = c; s <= qt; s += S) {
        const bool more = (s + S <= qt);
        if (more) issue_tile(cur ^ 1, (s + S) * 64);

        const unsigned short* Kc = &Ks[cur][0];
        const unsigned short* Vc = &Vts[cur][0];

        // S^T = K Q^T : lane holds C[kv = t4*16 + g4 + i][q = ln]
        f32x4 accS[4];
        __builtin_amdgcn_s_setprio(1);
#pragma unroll
        for (int t4 = 0; t4 < 4; t4++) {
            accS[t4] = (f32x4){0.f, 0.f, 0.f, 0.f};
#pragma unroll
            for (int kc = 0; kc < 2; kc++) {
                const int n = t4*16 + ln;
                bf16x8 kf = *(const bf16x8*)&Kc[n*64 + ((kc*4 + g) ^ (n & 7)) * 8];
                accS[t4] = __builtin_amdgcn_mfma_f32_16x16x32_bf16(kf, qf[kc], accS[t4], 0, 0, 0);
            }
        }
        __builtin_amdgcn_s_setprio(0);

        const bool diag = (s == qt);
#pragma unroll
        for (int t4 = 0; t4 < 4; t4++) {
            float pv[4];
#pragma unroll
            for (int i = 0; i < 4; i++) {
                float sv = accS[t4][i];
                if (diag && (t4*16 + g4 + i > w*16 + ln)) sv = -1e30f;  // kv > q
                const float p = exp2f(sv);
                lrow += p;
                pv[i] = p;
            }
            uint2 pk2;
            pk2.x = cvt_pk_bf16(pv[0], pv[1]);
            pk2.y = cvt_pk_bf16(pv[2], pv[3]);
            *(uint2*)&Pw[pwbase + ((t4*2 + pslotx) ^ (ln & 7)) * 8] = pk2;
        }

        __builtin_amdgcn_s_setprio(1);
#pragma unroll
        for (int kc = 0; kc < 2; kc++) {
            bf16x8 pa = *(const bf16x8*)&Pw[ln*64 + ((kc*4 + g) ^ (ln & 7)) * 8];
#pragma unroll
            for (int ht = 0; ht < 4; ht++) {
                const int vr2 = ht*16 + ln;
                bf16x8 vf = *(const bf16x8*)&Vc[vr2*64 + ((kc*4 + g) ^ (vr2 & 7)) * 8];
                accO[ht] = __builtin_amdgcn_mfma_f32_16x16x32_bf16(pa, vf, accO[ht], 0, 0, 0);
            }
        }
        __builtin_amdgcn_s_setprio(0);

        if (!more) break;          // final tile: no trailing barrier needed
        __syncthreads();
        cur ^= 1;
    }

    // full row-sum for q-row ln: sum across the 4 g-lanes
    lrow += __shfl_xor(lrow, 16);
    lrow += __shfl_xor(lrow, 32);

    char* Op = pbase + (size_t)((b * 32 + qt) * S + c) * PBYTES;
    unsigned short* Ob = (unsigned short*)Op;
    float* Lp = (float*)(Op + 8192);
#pragma unroll
    for (int ht = 0; ht < 4; ht++)
#pragma unroll
        for (int i = 0; i < 4; i++)
            Ob[(size_t)(w*16 + g4 + i) * 64 + ht*16 + ln] = f2bf(accO[ht][i]);
    if (g == 0)
        Lp[w*16 + ln] = lrow;
}

// ---------------------------------------------------------------------------
// Combine: out = sum_c O_c / sum_c l_c (O bf16, l f32). 256 blocks (b,qt),
// 256 thr: row = t>>2 (0..63), colgroup = t&3 (16 cols). First chunk hoisted.
// ---------------------------------------------------------------------------
template<int S>
__global__ __launch_bounds__(256)
void combine_kernel(const char* __restrict__ pbase, float* __restrict__ out)
{
    const int bid = blockIdx.x;
    const int b   = bid & 7;
    const int qt  = 31 - (bid >> 3);
    const int t   = threadIdx.x;
    const int r   = t >> 2;
    const int cg  = t & 3;

    const int nch = (qt + 1 < S) ? (qt + 1) : S;
    const char* P0 = pbase + (size_t)(b * 32 + qt) * S * PBYTES;

    float denom;
    float o[16];
    {
        const unsigned short* Ob = (const unsigned short*)P0;
        denom = ((const float*)(P0 + 8192))[r];
#pragma unroll
        for (int j = 0; j < 4; j++) {
            us4 v = *(const us4*)&Ob[(size_t)r * 64 + cg * 16 + j * 4];
#pragma unroll
            for (int e = 0; e < 4; e++) {
                union { unsigned u; float f; } cv;
                cv.u = ((unsigned)v[e]) << 16;
                o[j*4 + e] = cv.f;
            }
        }
    }
    for (int cc = 1; cc < nch; cc++) {
        const char* Pc = P0 + (size_t)cc * PBYTES;
        const unsigned short* Ob = (const unsigned short*)Pc;
        denom += ((const float*)(Pc + 8192))[r];
#pragma unroll
        for (int j = 0; j < 4; j++) {
            us4 v = *(const us4*)&Ob[(size_t)r * 64 + cg * 16 + j * 4];
#pragma unroll
            for (int e = 0; e < 4; e++) {
                union { unsigned u; float f; } cv;
                cv.u = ((unsigned)v[e]) << 16;
                o[j*4 + e] += cv.f;
            }
        }
    }
    const float inv = 1.f / denom;
    float* ob = out + ((size_t)b * Tz + qt * 64 + r) * Hz + cg * 16;
#pragma unroll
    for (int j = 0; j < 4; j++)
        *(float4*)&ob[j * 4] = make_float4(o[j*4] * inv, o[j*4+1] * inv,
                                           o[j*4+2] * inv, o[j*4+3] * inv);
}

extern "C" void kernel_launch(void* const* d_in, const int* in_sizes, int n_in,
                              void* d_out, int out_size, void* d_ws, size_t ws_size,
                              hipStream_t stream) {
    const float* x  = (const float*)d_in[0];
    const float* Wq = (const float*)d_in[1];
    const float* Wk = (const float*)d_in[2];
    const float* Wv = (const float*)d_in[3];

    unsigned short* Wti = (unsigned short*)d_ws;           // 16*12288 = 196608
    unsigned short* qg  = Wti + 196608;
    unsigned short* kg  = qg + (size_t)BT * Hz;
    unsigned short* vT  = kg + (size_t)BT * Hz;            // [b][h][t]
    const size_t baseShorts = 196608 + 3 * (size_t)BT * Hz;
    char* pbase = (char*)d_ws + baseShorts * 2;
    float* out = (float*)d_out;

    wprep_kernel<<<48, 256, 0, stream>>>(Wq, Wk, Wv, Wti);
    qkv_mfma_kernel<<<512, 256, 0, stream>>>(x, Wti, qg, kg, vT);

    const size_t base = baseShorts * 2;
    const size_t per  = (size_t)8 * 32 * PBYTES;           // bytes per split-way
    if (ws_size >= base + 4 * per) {
        attn_mfma_kernel<4><<<8 * 32 * 4, 256, 0, stream>>>(qg, kg, vT, pbase);
        combine_kernel<4><<<256, 256, 0, stream>>>(pbase, out);
    } else {
        attn_mfma_kernel<1><<<8 * 32 * 1, 256, 0, stream>>>(qg, kg, vT, pbase);
        combine_kernel<1><<<256, 256, 0, stream>>>(pbase, out);
    }
}

// Round 22
// 44.092 us; speedup vs baseline: 1.1759x; 1.0420x over previous
//
#include <hip/hip_runtime.h>
#include <math.h>

#define Bz 8
#define Tz 2048
#define Cz 1024
#define Hz 64
#define BT (Bz*Tz)      // 16384 rows

typedef __attribute__((ext_vector_type(8))) short bf16x8;
typedef __attribute__((ext_vector_type(4))) float f32x4;
typedef __attribute__((ext_vector_type(4))) unsigned short us4;

#define PBYTES 8448     // per-partial bytes: 64*64 bf16 O (8192) + 64 f32 l (256)

__device__ __forceinline__ unsigned short f2bf(float f) {
    union { float f; unsigned u; } v; v.f = f;
    unsigned r = v.u + 0x7fffu + ((v.u >> 16) & 1u);   // RNE
    return (unsigned short)(r >> 16);
}

__device__ __forceinline__ bf16x8 pack8(const float* s) {
    bf16x8 r;
#pragma unroll
    for (int j = 0; j < 8; j++) r[j] = (short)f2bf(s[j]);
    return r;
}

// HW packed f32->bf16 (RNE): D[15:0]=bf16(lo), D[31:16]=bf16(hi)
__device__ __forceinline__ unsigned cvt_pk_bf16(float lo, float hi) {
    unsigned r;
    asm volatile("v_cvt_pk_bf16_f32 %0, %1, %2" : "=v"(r) : "v"(lo), "v"(hi));
    return r;
}

__device__ __forceinline__ bf16x8 cvt8(float4 a, float4 b) {
    union { unsigned u[4]; bf16x8 v; } r;
    r.u[0] = cvt_pk_bf16(a.x, a.y);
    r.u[1] = cvt_pk_bf16(a.z, a.w);
    r.u[2] = cvt_pk_bf16(b.x, b.y);
    r.u[3] = cvt_pk_bf16(b.z, b.w);
    return r.v;
}

// async global->LDS, 16B/lane: lane i -> ldsbase + i*16 (wave-uniform base)
__device__ __forceinline__ void gload16(const void* g, void* l) {
    __builtin_amdgcn_global_load_lds(
        (const __attribute__((address_space(1))) void*)g,
        (__attribute__((address_space(3))) void*)l, 16, 0, 0);
}

// ---------------------------------------------------------------------------
// W prep -> per-chunk swizzled LDS image (identity-DMA format).
// img[kt*12288 + n*64 + phys*8 + e] = W[k0 + logical*8 + e][n], phys = logical^(n&7)
// ---------------------------------------------------------------------------
__global__ __launch_bounds__(256)
void wprep_kernel(const float* __restrict__ Wq, const float* __restrict__ Wk,
                  const float* __restrict__ Wv, unsigned short* __restrict__ Wti)
{
    __shared__ float T[64][65];
    const int mat = blockIdx.x >> 4;
    const int kt  = blockIdx.x & 15;
    const int k0  = kt * 64;
    const float* W = (mat == 0) ? Wq : (mat == 1) ? Wk : Wv;
    const int t  = threadIdx.x;
    const int rr = t >> 2;
    const int c4 = (t & 3) * 16;
#pragma unroll
    for (int j = 0; j < 4; j++) {
        float4 w4 = *(const float4*)&W[(size_t)(k0 + rr) * Hz + c4 + j * 4];
        T[c4 + j*4 + 0][rr] = w4.x;
        T[c4 + j*4 + 1][rr] = w4.y;
        T[c4 + j*4 + 2][rr] = w4.z;
        T[c4 + j*4 + 3][rr] = w4.w;
    }
    __syncthreads();
    const int nn  = t >> 2;
    const int sl0 = (t & 3) * 2;
    const int n   = mat * 64 + nn;
    float tmp[16];
#pragma unroll
    for (int j = 0; j < 16; j++) tmp[j] = T[nn][sl0 * 8 + j];
    unsigned short* base = &Wti[(size_t)kt * 12288 + n * 64];
    *(bf16x8*)&base[((sl0    ) ^ (n & 7)) * 8] = pack8(tmp);
    *(bf16x8*)&base[((sl0 + 1) ^ (n & 7)) * 8] = pack8(tmp + 8);
}

// ---------------------------------------------------------------------------
// QKV projection v10: 64 rows x 64 cols (ONE matrix) per block, grid 768
// (3 blocks/CU, 12 waves/CU), counted-vmcnt distance-1 (r18 schedule),
// LDS 48 KB (2 x [16 KB x-fp32 + 8 KB W-bf16]). 6 vmem/wave/chunk ->
// vmcnt(6). 3 mats of same row-tile share an XCD (x L2-resident).
// q output pre-scaled by log2(e)/8.
// ---------------------------------------------------------------------------
__global__ __launch_bounds__(256, 4)
void qkv_mfma_kernel(const float* __restrict__ x, const unsigned short* __restrict__ Wti,
                     unsigned short* __restrict__ qg, unsigned short* __restrict__ kg,
                     unsigned short* __restrict__ vT)
{
    __shared__ __align__(16) float          xsF[2][64 * 64];   // fp32, swizzled 16B slots
    __shared__ __align__(16) unsigned short ws [2][64 * 64];   // bf16, swizzled

    const int t    = threadIdx.x;
    const int bid  = blockIdx.x;
    const int low  = bid & 7;
    const int hi   = bid >> 3;          // 0..95
    const int mat  = hi % 3;
    const int M0   = ((hi / 3) * 8 + low) * 64;   // mtile 0..255
    const int ln   = t & 15;
    const int g    = (t & 63) >> 4;
    const int g4   = g * 4;
    const int w    = t >> 6;            // 0..3, wave's 16 rows
    const int lane = t & 63;
    const float SCq = 0.18033688011112042f;   // log2(e)/8

    f32x4 acc[4];
#pragma unroll
    for (int i = 0; i < 4; i++) acc[i] = (f32x4){0.f, 0.f, 0.f, 0.f};

    // 6 vmem ops per wave per chunk (4 x + 2 W)
    auto issue = [&](int buf, int kt) {
        const int k0 = kt * 64;
#pragma unroll
        for (int j = 0; j < 4; j++) {
            const int r  = w * 16 + j * 4 + (lane >> 4);
            const int sl = (lane & 15) ^ (r & 7);
            gload16(&x[(size_t)(M0 + r) * Cz + k0 + sl * 4],
                    &xsF[buf][(w * 16 + j * 4) * 64]);
        }
#pragma unroll
        for (int j = 0; j < 2; j++) {
            const int jj = w * 2 + j;   // 0..7 (8-row groups of this mat's 64 cols)
            gload16(&Wti[(size_t)kt * 12288 + (size_t)(mat * 64 + jj * 8) * 64 + lane * 8],
                    &ws[buf][jj * 512]);
        }
    };

    // prologue: 2 chunks in flight; publish chunk 0 (keep chunk 1's 6 in flight)
    issue(0, 0); issue(1, 1);
    asm volatile("s_waitcnt vmcnt(6)" ::: "memory");
    __builtin_amdgcn_sched_barrier(0);
    __builtin_amdgcn_s_barrier();

    for (int kt = 0; kt < 16; ++kt) {
        const int bufR = kt & 1;
        bf16x8 af[2];
        const int row = w * 16 + ln;
#pragma unroll
        for (int kc = 0; kc < 2; kc++) {
            const int s0 = kc * 8 + g * 2;
            float4 fa = *(const float4*)&xsF[bufR][row * 64 + ((s0    ) ^ (row & 7)) * 4];
            float4 fb = *(const float4*)&xsF[bufR][row * 64 + ((s0 + 1) ^ (row & 7)) * 4];
            af[kc] = cvt8(fa, fb);
        }
        __builtin_amdgcn_s_setprio(1);
#pragma unroll
        for (int ct = 0; ct < 4; ct++) {
            const int nn = ct * 16 + ln;            // local col 0..63
#pragma unroll
            for (int kc = 0; kc < 2; kc++) {
                bf16x8 bf = *(const bf16x8*)&ws[bufR][nn * 64 + ((kc*4 + g) ^ (nn & 7)) * 8];
                acc[ct] = __builtin_amdgcn_mfma_f32_16x16x32_bf16(af[kc], bf, acc[ct], 0, 0, 0);
            }
        }
        __builtin_amdgcn_s_setprio(0);

        if (kt == 15) break;

        // ---- all waves done READING bufR ----
        __builtin_amdgcn_sched_barrier(0);
        __builtin_amdgcn_s_barrier();

        // ---- refill bufR with chunk kt+2; retire chunk kt+1 (counted) ----
        if (kt + 2 < 16) {
            issue(bufR, kt + 2);
            asm volatile("s_waitcnt vmcnt(6)" ::: "memory");   // c(kt+1) done; c(kt+2) in flight
        } else {
            asm volatile("s_waitcnt vmcnt(0)" ::: "memory");   // c15 done
        }
        __builtin_amdgcn_sched_barrier(0);
        __builtin_amdgcn_s_barrier();
    }

    // epilogue: D col = ct*16 + ln, row = M0 + w*16 + g4 + i; route by mat
    const int m0 = M0 + w * 16 + g4;
    if (mat == 0) {
#pragma unroll
        for (int ct = 0; ct < 4; ct++)
#pragma unroll
            for (int i = 0; i < 4; i++)
                qg[(size_t)(m0 + i) * Hz + ct * 16 + ln] = f2bf(acc[ct][i] * SCq);
    } else if (mat == 1) {
#pragma unroll
        for (int ct = 0; ct < 4; ct++)
#pragma unroll
            for (int i = 0; i < 4; i++)
                kg[(size_t)(m0 + i) * Hz + ct * 16 + ln] = f2bf(acc[ct][i]);
    } else {
        const int b = m0 >> 11, tt = m0 & 2047;
#pragma unroll
        for (int ct = 0; ct < 4; ct++) {
            const int h = ct * 16 + ln;
            us4 pk;
#pragma unroll
            for (int i = 0; i < 4; i++) pk[i] = f2bf(acc[ct][i]);
            *(us4*)&vT[((size_t)b * Hz + h) * Tz + tt] = pk;
        }
    }
}

// ---------------------------------------------------------------------------
// Flash attention (r20/r21), S-way strided KV-split, batch->XCD affinity.
// SWAPPED QK^T; fixed-max softmax; dbuf gload_lds, ONE barrier/tile
// (skipped on the final tile). Partials: O bf16 + l f32.
// ---------------------------------------------------------------------------
template<int S>
__global__ __launch_bounds__(256, 4)
void attn_mfma_kernel(const unsigned short* __restrict__ qg,
                      const unsigned short* __restrict__ kg,
                      const unsigned short* __restrict__ vT,
                      char* __restrict__ pbase)
{
    __shared__ __align__(16) unsigned short Ks [2][64 * 64];
    __shared__ __align__(16) unsigned short Vts[2][64 * 64];
    __shared__ __align__(16) unsigned short Ps [4 * 16 * 64];

    const int bid = blockIdx.x;
    const int b   = bid & 7;                   // XCD affinity
    const int r0  = bid >> 3;
    const int c   = r0 % S;
    const int qt  = 31 - (r0 / S);             // heavy-first
    if (c > qt) return;
    const int q0  = qt * 64;

    const int t  = threadIdx.x;
    const int ln = t & 15;
    const int g  = (t & 63) >> 4;
    const int g4 = g * 4;
    const int w  = t >> 6;
    const int l6 = t & 63;

    const unsigned short* qb = qg + (size_t)b * Tz * Hz;
    const unsigned short* kb = kg + (size_t)b * Tz * Hz;
    const unsigned short* vb = vT + (size_t)b * Hz * Tz;

    const int rl  = l6 >> 3;
    const int swz = ((l6 & 7) ^ rl) * 8;
    auto issue_tile = [&](int buf, int s0) {
#pragma unroll
        for (int qq = 0; qq < 2; qq++) {
            const int row = w*16 + qq*8 + rl;
            gload16(&kb[(size_t)(s0 + row) * Hz + swz],
                    &Ks[buf][(w*16 + qq*8) * 64]);
            gload16(&vb[(size_t)row * Tz + s0 + swz],
                    &Vts[buf][(w*16 + qq*8) * 64]);
        }
    };

    issue_tile(0, c * 64);

    bf16x8 qf[2];
    {
        const int qrow = q0 + w*16 + ln;
        qf[0] = *(const bf16x8*)&qb[(size_t)qrow * Hz + g*8];
        qf[1] = *(const bf16x8*)&qb[(size_t)qrow * Hz + 32 + g*8];
    }

    f32x4 accO[4];
#pragma unroll
    for (int i = 0; i < 4; i++) accO[i] = (f32x4){0.f, 0.f, 0.f, 0.f};
    float lrow = 0.f;
    unsigned short* Pw = &Ps[w * 1024];
    const int pwbase = ln*64 + (g & 1) * 4;
    const int pslotx = (g >> 1);

    __syncthreads();
    int cur = 0;

    for (int s = c; s <= qt; s += S) {
        const bool more = (s + S <= qt);
        if (more) issue_tile(cur ^ 1, (s + S) * 64);

        const unsigned short* Kc = &Ks[cur][0];
        const unsigned short* Vc = &Vts[cur][0];

        // S^T = K Q^T : lane holds C[kv = t4*16 + g4 + i][q = ln]
        f32x4 accS[4];
        __builtin_amdgcn_s_setprio(1);
#pragma unroll
        for (int t4 = 0; t4 < 4; t4++) {
            accS[t4] = (f32x4){0.f, 0.f, 0.f, 0.f};
#pragma unroll
            for (int kc = 0; kc < 2; kc++) {
                const int n = t4*16 + ln;
                bf16x8 kf = *(const bf16x8*)&Kc[n*64 + ((kc*4 + g) ^ (n & 7)) * 8];
                accS[t4] = __builtin_amdgcn_mfma_f32_16x16x32_bf16(kf, qf[kc], accS[t4], 0, 0, 0);
            }
        }
        __builtin_amdgcn_s_setprio(0);

        const bool diag = (s == qt);
#pragma unroll
        for (int t4 = 0; t4 < 4; t4++) {
            float pv[4];
#pragma unroll
            for (int i = 0; i < 4; i++) {
                float sv = accS[t4][i];
                if (diag && (t4*16 + g4 + i > w*16 + ln)) sv = -1e30f;  // kv > q
                const float p = exp2f(sv);
                lrow += p;
                pv[i] = p;
            }
            uint2 pk2;
            pk2.x = cvt_pk_bf16(pv[0], pv[1]);
            pk2.y = cvt_pk_bf16(pv[2], pv[3]);
            *(uint2*)&Pw[pwbase + ((t4*2 + pslotx) ^ (ln & 7)) * 8] = pk2;
        }

        __builtin_amdgcn_s_setprio(1);
#pragma unroll
        for (int kc = 0; kc < 2; kc++) {
            bf16x8 pa = *(const bf16x8*)&Pw[ln*64 + ((kc*4 + g) ^ (ln & 7)) * 8];
#pragma unroll
            for (int ht = 0; ht < 4; ht++) {
                const int vr2 = ht*16 + ln;
                bf16x8 vf = *(const bf16x8*)&Vc[vr2*64 + ((kc*4 + g) ^ (vr2 & 7)) * 8];
                accO[ht] = __builtin_amdgcn_mfma_f32_16x16x32_bf16(pa, vf, accO[ht], 0, 0, 0);
            }
        }
        __builtin_amdgcn_s_setprio(0);

        if (!more) break;          // final tile: no trailing barrier needed
        __syncthreads();
        cur ^= 1;
    }

    // full row-sum for q-row ln: sum across the 4 g-lanes
    lrow += __shfl_xor(lrow, 16);
    lrow += __shfl_xor(lrow, 32);

    char* Op = pbase + (size_t)((b * 32 + qt) * S + c) * PBYTES;
    unsigned short* Ob = (unsigned short*)Op;
    float* Lp = (float*)(Op + 8192);
#pragma unroll
    for (int ht = 0; ht < 4; ht++)
#pragma unroll
        for (int i = 0; i < 4; i++)
            Ob[(size_t)(w*16 + g4 + i) * 64 + ht*16 + ln] = f2bf(accO[ht][i]);
    if (g == 0)
        Lp[w*16 + ln] = lrow;
}

// ---------------------------------------------------------------------------
// Combine: out = sum_c O_c / sum_c l_c (O bf16, l f32). 256 blocks (b,qt),
// 256 thr: row = t>>2 (0..63), colgroup = t&3 (16 cols). First chunk hoisted.
// ---------------------------------------------------------------------------
template<int S>
__global__ __launch_bounds__(256)
void combine_kernel(const char* __restrict__ pbase, float* __restrict__ out)
{
    const int bid = blockIdx.x;
    const int b   = bid & 7;
    const int qt  = 31 - (bid >> 3);
    const int t   = threadIdx.x;
    const int r   = t >> 2;
    const int cg  = t & 3;

    const int nch = (qt + 1 < S) ? (qt + 1) : S;
    const char* P0 = pbase + (size_t)(b * 32 + qt) * S * PBYTES;

    float denom;
    float o[16];
    {
        const unsigned short* Ob = (const unsigned short*)P0;
        denom = ((const float*)(P0 + 8192))[r];
#pragma unroll
        for (int j = 0; j < 4; j++) {
            us4 v = *(const us4*)&Ob[(size_t)r * 64 + cg * 16 + j * 4];
#pragma unroll
            for (int e = 0; e < 4; e++) {
                union { unsigned u; float f; } cv;
                cv.u = ((unsigned)v[e]) << 16;
                o[j*4 + e] = cv.f;
            }
        }
    }
    for (int cc = 1; cc < nch; cc++) {
        const char* Pc = P0 + (size_t)cc * PBYTES;
        const unsigned short* Ob = (const unsigned short*)Pc;
        denom += ((const float*)(Pc + 8192))[r];
#pragma unroll
        for (int j = 0; j < 4; j++) {
            us4 v = *(const us4*)&Ob[(size_t)r * 64 + cg * 16 + j * 4];
#pragma unroll
            for (int e = 0; e < 4; e++) {
                union { unsigned u; float f; } cv;
                cv.u = ((unsigned)v[e]) << 16;
                o[j*4 + e] += cv.f;
            }
        }
    }
    const float inv = 1.f / denom;
    float* ob = out + ((size_t)b * Tz + qt * 64 + r) * Hz + cg * 16;
#pragma unroll
    for (int j = 0; j < 4; j++)
        *(float4*)&ob[j * 4] = make_float4(o[j*4] * inv, o[j*4+1] * inv,
                                           o[j*4+2] * inv, o[j*4+3] * inv);
}

extern "C" void kernel_launch(void* const* d_in, const int* in_sizes, int n_in,
                              void* d_out, int out_size, void* d_ws, size_t ws_size,
                              hipStream_t stream) {
    const float* x  = (const float*)d_in[0];
    const float* Wq = (const float*)d_in[1];
    const float* Wk = (const float*)d_in[2];
    const float* Wv = (const float*)d_in[3];

    unsigned short* Wti = (unsigned short*)d_ws;           // 16*12288 = 196608
    unsigned short* qg  = Wti + 196608;
    unsigned short* kg  = qg + (size_t)BT * Hz;
    unsigned short* vT  = kg + (size_t)BT * Hz;            // [b][h][t]
    const size_t baseShorts = 196608 + 3 * (size_t)BT * Hz;
    char* pbase = (char*)d_ws + baseShorts * 2;
    float* out = (float*)d_out;

    wprep_kernel<<<48, 256, 0, stream>>>(Wq, Wk, Wv, Wti);
    qkv_mfma_kernel<<<768, 256, 0, stream>>>(x, Wti, qg, kg, vT);

    const size_t base = baseShorts * 2;
    const size_t per  = (size_t)8 * 32 * PBYTES;           // bytes per split-way
    if (ws_size >= base + 4 * per) {
        attn_mfma_kernel<4><<<8 * 32 * 4, 256, 0, stream>>>(qg, kg, vT, pbase);
        combine_kernel<4><<<256, 256, 0, stream>>>(pbase, out);
    } else {
        attn_mfma_kernel<1><<<8 * 32 * 1, 256, 0, stream>>>(qg, kg, vT, pbase);
        combine_kernel<1><<<256, 256, 0, stream>>>(pbase, out);
    }
}